// Round 1
// baseline (569.370 us; speedup 1.0000x reference)
//
#include <hip/hip_runtime.h>

// Problem: single causal attention head.
// B=4, T=4096, C=384 (n_embd), H=16 (head_size). fp32 in, fp32 out.
// k = x@Wk, q = x@Wq, v = x@Wv  (W stored [C,H])
// wei = softmax(causal(q k^T * H^-0.5)); out = wei @ v.

constexpr int B_DIM = 4;
constexpr int T_SEQ = 4096;
constexpr int C_DIM = 384;
constexpr int H_DIM = 16;
constexpr int NROW = B_DIM * T_SEQ; // 16384

// ---------------------------------------------------------------------------
// Kernel 1: QKV projection.  thread = (row, matrix m). Wave-uniform m so the
// W loads are scalar (s_load) and broadcast; x row read via float4 (L1 reuses
// the 64 row-lines across the 96 c-iterations; 3 waves/block share rows).
// grid = 192 blocks * 256 thr = 768 waves = 256 row-groups * 3 matrices.
// ---------------------------------------------------------------------------
__global__ __launch_bounds__(256) void qkv_proj(
    const float* __restrict__ x,
    const float* __restrict__ Wk, const float* __restrict__ Wq,
    const float* __restrict__ Wv,
    float* __restrict__ ks, float* __restrict__ qs, float* __restrict__ vs) {
  const int tid  = threadIdx.x;
  const int w    = tid >> 6;
  const int lane = tid & 63;
  const int gw   = blockIdx.x * 4 + w;       // global wave id, 0..767
  int m          = gw % 3;                    // matrix select (wave-uniform)
  const int row  = (gw / 3) * 64 + lane;      // 0..16383
  m = __builtin_amdgcn_readfirstlane(m);      // force scalar → s_load path for W

  const float* __restrict__ W = (m == 0) ? Wk : (m == 1) ? Wq : Wv;
  float* __restrict__ out     = (m == 0) ? ks : (m == 1) ? qs : vs;

  float acc[H_DIM];
#pragma unroll
  for (int h = 0; h < H_DIM; ++h) acc[h] = 0.f;

  const float4* __restrict__ xr =
      reinterpret_cast<const float4*>(x + (size_t)row * C_DIM);
#pragma unroll 4
  for (int c4 = 0; c4 < C_DIM / 4; ++c4) {    // 96 iters
    const float4 xv = xr[c4];
    const float* __restrict__ Wc = W + c4 * 4 * H_DIM;  // uniform address
#pragma unroll
    for (int cc = 0; cc < 4; ++cc) {
      const float xc = (&xv.x)[cc];
#pragma unroll
      for (int h = 0; h < H_DIM; ++h)
        acc[h] = fmaf(xc, Wc[cc * H_DIM + h], acc[h]);
    }
  }

  float4* __restrict__ orow = reinterpret_cast<float4*>(out + (size_t)row * H_DIM);
  orow[0] = make_float4(acc[0],  acc[1],  acc[2],  acc[3]);
  orow[1] = make_float4(acc[4],  acc[5],  acc[6],  acc[7]);
  orow[2] = make_float4(acc[8],  acc[9],  acc[10], acc[11]);
  orow[3] = make_float4(acc[12], acc[13], acc[14], acc[15]);
}

// ---------------------------------------------------------------------------
// Kernel 2: causal flash attention, fp32 VALU.
// block = 256 thr: qi = tid>>4 (16 query rows), seg = tid&15 (16 key segments
// of 4 keys → BK=64). All 16 segs of a query row live in one 16-lane group →
// softmax stats via width-16 __shfl_xor, NO barriers, NO LDS.
// K/V read straight from global: 16 distinct 16B addresses per wave-load →
// L1 broadcast; K+V per batch = 512 KB → L2-resident.
// Load balance: block handles query-tile pair (qt, 255-qt) → ~66 key-tiles
// per block for every block. grid = 4 batches * 128 pairs = 512 blocks.
// ---------------------------------------------------------------------------
__global__ __launch_bounds__(256) void flash_head(
    const float* __restrict__ qs, const float* __restrict__ ks,
    const float* __restrict__ vs, float* __restrict__ out) {
  const int tid = threadIdx.x;
  const int qi  = tid >> 4;   // 0..15
  const int seg = tid & 15;   // 0..15
  const int b   = blockIdx.x >> 7;   // 0..3
  const int pr  = blockIdx.x & 127;  // 0..127

  // fold softmax scale (H^-0.5 = 0.25) and log2(e) into q → exp2f = v_exp_f32
  const float SC = 0.25f * 1.44269504088896f;

  for (int half = 0; half < 2; ++half) {
    const int qt  = half ? (255 - pr) : pr;
    const int r0  = qt * 16;
    const int row = r0 + qi;  // query row in [0, 4096)

    float q[H_DIM];
    {
      const float4* __restrict__ qr =
          reinterpret_cast<const float4*>(qs + ((size_t)b * T_SEQ + row) * H_DIM);
#pragma unroll
      for (int i = 0; i < 4; ++i) {
        const float4 t = qr[i];
        q[4 * i + 0] = t.x * SC; q[4 * i + 1] = t.y * SC;
        q[4 * i + 2] = t.z * SC; q[4 * i + 3] = t.w * SC;
      }
    }

    float o[H_DIM];
#pragma unroll
    for (int h = 0; h < H_DIM; ++h) o[h] = 0.f;
    float mrow = -1e30f, lrow = 0.f;

    const int ktmax = (r0 + 15) >> 6;  // inclusive
    for (int kt = 0; kt <= ktmax; ++kt) {
      const int t0 = kt << 6;
      float s[4];
#pragma unroll
      for (int jj = 0; jj < 4; ++jj) {
        const int j = t0 + seg * 4 + jj;
        const float4* __restrict__ kr =
            reinterpret_cast<const float4*>(ks + ((size_t)b * T_SEQ + j) * H_DIM);
        float a = 0.f;
#pragma unroll
        for (int i = 0; i < 4; ++i) {
          const float4 kv = kr[i];
          a = fmaf(q[4 * i + 0], kv.x, a);
          a = fmaf(q[4 * i + 1], kv.y, a);
          a = fmaf(q[4 * i + 2], kv.z, a);
          a = fmaf(q[4 * i + 3], kv.w, a);
        }
        s[jj] = (j > row) ? -1e30f : a;  // causal mask
      }

      // row max across the 16 segs (one 16-lane group)
      float lm = fmaxf(fmaxf(s[0], s[1]), fmaxf(s[2], s[3]));
#pragma unroll
      for (int d = 1; d < 16; d <<= 1) lm = fmaxf(lm, __shfl_xor(lm, d, 16));

      const float mn    = fmaxf(mrow, lm);
      const float alpha = exp2f(mrow - mn);

      float p[4], ls = 0.f;
#pragma unroll
      for (int jj = 0; jj < 4; ++jj) { p[jj] = exp2f(s[jj] - mn); ls += p[jj]; }
      lrow = lrow * alpha + ls;
#pragma unroll
      for (int h = 0; h < H_DIM; ++h) o[h] *= alpha;

#pragma unroll
      for (int jj = 0; jj < 4; ++jj) {
        const int j = t0 + seg * 4 + jj;
        const float4* __restrict__ vr =
            reinterpret_cast<const float4*>(vs + ((size_t)b * T_SEQ + j) * H_DIM);
#pragma unroll
        for (int i = 0; i < 4; ++i) {
          const float4 vv = vr[i];
          o[4 * i + 0] = fmaf(p[jj], vv.x, o[4 * i + 0]);
          o[4 * i + 1] = fmaf(p[jj], vv.y, o[4 * i + 1]);
          o[4 * i + 2] = fmaf(p[jj], vv.z, o[4 * i + 2]);
          o[4 * i + 3] = fmaf(p[jj], vv.w, o[4 * i + 3]);
        }
      }
      mrow = mn;
    }

    // reduce l and o across the 16 segs
#pragma unroll
    for (int d = 1; d < 16; d <<= 1) lrow += __shfl_xor(lrow, d, 16);
#pragma unroll
    for (int h = 0; h < H_DIM; ++h) {
#pragma unroll
      for (int d = 1; d < 16; d <<= 1) o[h] += __shfl_xor(o[h], d, 16);
    }

    if (seg == 0) {
      const float rinv = 1.0f / lrow;
      float4* __restrict__ orow =
          reinterpret_cast<float4*>(out + ((size_t)b * T_SEQ + row) * H_DIM);
      orow[0] = make_float4(o[0] * rinv,  o[1] * rinv,  o[2] * rinv,  o[3] * rinv);
      orow[1] = make_float4(o[4] * rinv,  o[5] * rinv,  o[6] * rinv,  o[7] * rinv);
      orow[2] = make_float4(o[8] * rinv,  o[9] * rinv,  o[10] * rinv, o[11] * rinv);
      orow[3] = make_float4(o[12] * rinv, o[13] * rinv, o[14] * rinv, o[15] * rinv);
    }
  }
}

extern "C" void kernel_launch(void* const* d_in, const int* in_sizes, int n_in,
                              void* d_out, int out_size, void* d_ws, size_t ws_size,
                              hipStream_t stream) {
  const float* x  = (const float*)d_in[0];
  const float* Wk = (const float*)d_in[1];
  const float* Wq = (const float*)d_in[2];
  const float* Wv = (const float*)d_in[3];
  float* outp = (float*)d_out;

  // workspace: k, q, v  each [B*T, H] fp32 = 1 MB
  float* ks = (float*)d_ws;
  float* qs = ks + (size_t)NROW * H_DIM;
  float* vs = qs + (size_t)NROW * H_DIM;

  qkv_proj<<<192, 256, 0, stream>>>(x, Wk, Wq, Wv, ks, qs, vs);
  flash_head<<<512, 256, 0, stream>>>(qs, ks, vs, outp);
}

// Round 2
// 176.640 us; speedup vs baseline: 3.2233x; 3.2233x over previous
//
#include <hip/hip_runtime.h>

// Causal attention head. B=4, T=4096, C=384, H=16. fp32 in/out.
// Round 2: bf16 MFMA flash attention (16x16x32_bf16, verified layouts only).
//  - qkv_proj (fp32 VALU, proven) now emits: Q bf16 [row][32] (scaled by
//    0.25*log2e, h>=16 zero-padded), K bf16 [row][16], V^T bf16 [b][16][T].
//  - flash_mfma: block=(b,qtile of 16 rows), 4 waves split key chunks of 64,
//    online softmax on MFMA C-fragments, P->A-layout via wave-private LDS
//    (stride 72 shorts = 144B: 16B-aligned, ~2-way banks), merge via LDS.

constexpr int B_DIM = 4;
constexpr int T_SEQ = 4096;
constexpr int C_DIM = 384;
constexpr int H_DIM = 16;
constexpr int NROW  = B_DIM * T_SEQ; // 16384

typedef __bf16 bf16x8 __attribute__((ext_vector_type(8)));
typedef float  f32x4  __attribute__((ext_vector_type(4)));

__device__ __forceinline__ unsigned short f2bf(float f) {
  unsigned int u = __builtin_bit_cast(unsigned int, f);
  u += 0x7fffu + ((u >> 16) & 1u);   // RNE (inputs finite, no NaN path)
  return (unsigned short)(u >> 16);
}
__device__ __forceinline__ bf16x8 as_bf16x8(uint4 u) {
  return __builtin_bit_cast(bf16x8, u);
}

// ---------------------------------------------------------------------------
// Kernel 1: QKV projection (fp32 VALU), bf16 epilogue.
// thread = (row, matrix m), wave-uniform m -> scalar W loads.
// ---------------------------------------------------------------------------
__global__ __launch_bounds__(256) void qkv_proj(
    const float* __restrict__ x,
    const float* __restrict__ Wk, const float* __restrict__ Wq,
    const float* __restrict__ Wv,
    unsigned short* __restrict__ Kb,   // [NROW][16] bf16 (+slack)
    unsigned short* __restrict__ Qb,   // [NROW][32] bf16, scaled, padded
    unsigned short* __restrict__ VTb)  // [B][16][T] bf16
{
  const int tid  = threadIdx.x;
  const int w    = tid >> 6;
  const int lane = tid & 63;
  const int gw   = blockIdx.x * 4 + w;       // 0..767
  int m          = gw % 3;
  const int row  = (gw / 3) * 64 + lane;     // 0..16383
  m = __builtin_amdgcn_readfirstlane(m);

  const float* __restrict__ W = (m == 0) ? Wk : (m == 1) ? Wq : Wv;

  float acc[H_DIM];
#pragma unroll
  for (int h = 0; h < H_DIM; ++h) acc[h] = 0.f;

  const float4* __restrict__ xr =
      reinterpret_cast<const float4*>(x + (size_t)row * C_DIM);
#pragma unroll 8
  for (int c4 = 0; c4 < C_DIM / 4; ++c4) {   // 96 iters
    const float4 xv = xr[c4];
    const float* __restrict__ Wc = W + c4 * 4 * H_DIM;
#pragma unroll
    for (int cc = 0; cc < 4; ++cc) {
      const float xc = (&xv.x)[cc];
#pragma unroll
      for (int h = 0; h < H_DIM; ++h)
        acc[h] = fmaf(xc, Wc[cc * H_DIM + h], acc[h]);
    }
  }

  if (m == 1) {
    // Q: fold softmax scale * log2(e), pad h 16..31 with zeros
    const float SC = 0.25f * 1.44269504088896341f;
    unsigned int pk[8];
#pragma unroll
    for (int i = 0; i < 8; ++i)
      pk[i] = (unsigned int)f2bf(acc[2 * i] * SC) |
              ((unsigned int)f2bf(acc[2 * i + 1] * SC) << 16);
    uint4* qr = reinterpret_cast<uint4*>(Qb + ((size_t)row << 5));
    qr[0] = make_uint4(pk[0], pk[1], pk[2], pk[3]);
    qr[1] = make_uint4(pk[4], pk[5], pk[6], pk[7]);
    qr[2] = make_uint4(0, 0, 0, 0);
    qr[3] = make_uint4(0, 0, 0, 0);
  } else if (m == 0) {
    unsigned int pk[8];
#pragma unroll
    for (int i = 0; i < 8; ++i)
      pk[i] = (unsigned int)f2bf(acc[2 * i]) |
              ((unsigned int)f2bf(acc[2 * i + 1]) << 16);
    uint4* kr = reinterpret_cast<uint4*>(Kb + ((size_t)row << 4));
    kr[0] = make_uint4(pk[0], pk[1], pk[2], pk[3]);
    kr[1] = make_uint4(pk[4], pk[5], pk[6], pk[7]);
  } else {
    // V^T: [b][h][t]; lanes have consecutive t -> coalesced short stores
    const int bb = row >> 12, t = row & 4095;
#pragma unroll
    for (int h = 0; h < H_DIM; ++h)
      VTb[(((size_t)(bb * 16 + h)) << 12) + t] = f2bf(acc[h]);
  }
}

// ---------------------------------------------------------------------------
// Kernel 2: bf16 MFMA flash attention.
// grid = 1024 blocks: (b = blk>>8, qt = blk&255). block = 256 = 4 waves.
// Wave w handles 64-key chunks c = w, w+4, ... ; merge at end via LDS.
// ---------------------------------------------------------------------------
__global__ __launch_bounds__(256) void flash_mfma(
    const unsigned short* __restrict__ Qb,
    const unsigned short* __restrict__ Kb,
    const unsigned short* __restrict__ VTb,
    float* __restrict__ out)
{
  const int tid  = threadIdx.x;
  const int w    = tid >> 6;
  const int lane = tid & 63;
  const int quad = lane >> 4;
  const int col  = lane & 15;
  const int b    = blockIdx.x >> 8;
  const int qt   = blockIdx.x & 255;
  const int r0   = qt << 4;

  __shared__ __attribute__((aligned(16))) unsigned short Pl[4][16 * 72];
  __shared__ float mrg[4][12][64];

  // Q A-frag: A[m=col][k=quad*8+j] ; h>=16 are zeros (pad)
  const uint4* qp = reinterpret_cast<const uint4*>(
      Qb + (((size_t)(b * T_SEQ + r0 + col)) << 5) + quad * 8);
  const bf16x8 qa = as_bf16x8(qp[0]);

  f32x4 o = {0.f, 0.f, 0.f, 0.f};
  float m_[4], l_[4];
#pragma unroll
  for (int r = 0; r < 4; ++r) { m_[r] = -1e30f; l_[r] = 0.f; }

  unsigned short* P = Pl[w];
  const int nch = (qt + 4) >> 2;  // ceil((qt+1)/4) chunks of 64 keys

  for (int c = w; c < nch; c += 4) {
    const int kt0 = c << 2;
    float s[4][4];
#pragma unroll
    for (int t = 0; t < 4; ++t) {
      const int kt = kt0 + t;
      if (kt <= qt) {
        // K B-frag: B[k=quad*8+j][n=col] = K[key=kt*16+col][h=quad*8+j]
        // quads 2,3 read past the 16-short row (next row) -> garbage * Qpad0
        const uint4* kp = reinterpret_cast<const uint4*>(
            Kb + (((size_t)(b * T_SEQ + kt * 16 + col)) << 4) + quad * 8);
        f32x4 z = {0.f, 0.f, 0.f, 0.f};
        f32x4 sf = __builtin_amdgcn_mfma_f32_16x16x32_bf16(
            qa, as_bf16x8(kp[0]), z, 0, 0, 0);
        if (kt == qt) {
#pragma unroll
          for (int r = 0; r < 4; ++r)
            s[t][r] = (col > quad * 4 + r) ? -1e30f : sf[r];  // causal diag
        } else {
#pragma unroll
          for (int r = 0; r < 4; ++r) s[t][r] = sf[r];
        }
      } else {
#pragma unroll
        for (int r = 0; r < 4; ++r) s[t][r] = -1e30f;
      }
    }

    // per-row max: combine 4 tiles, then reduce across the 16-lane group
    float mloc[4];
#pragma unroll
    for (int r = 0; r < 4; ++r)
      mloc[r] = fmaxf(fmaxf(s[0][r], s[1][r]), fmaxf(s[2][r], s[3][r]));
#pragma unroll
    for (int d = 1; d < 16; d <<= 1) {
#pragma unroll
      for (int r = 0; r < 4; ++r)
        mloc[r] = fmaxf(mloc[r], __shfl_xor(mloc[r], d, 16));
    }
    float alpha[4];
#pragma unroll
    for (int r = 0; r < 4; ++r) {
      const float mn = fmaxf(m_[r], mloc[r]);
      alpha[r] = exp2f(m_[r] - mn);
      m_[r] = mn;
    }

    // p = exp2(s - m); stash as bf16 into wave-private LDS P tile [16][72]
    float lsum[4] = {0.f, 0.f, 0.f, 0.f};
#pragma unroll
    for (int t = 0; t < 4; ++t) {
#pragma unroll
      for (int r = 0; r < 4; ++r) {
        const float p = exp2f(s[t][r] - m_[r]);
        lsum[r] += p;
        P[(quad * 4 + r) * 72 + t * 16 + col] = f2bf(p);
      }
    }
#pragma unroll
    for (int r = 0; r < 4; ++r) {
      l_[r] = l_[r] * alpha[r] + lsum[r];
      o[r] *= alpha[r];
    }

    // PV: O += P[16x32] * V[32x16], twice (keys c*64 .. c*64+63)
#pragma unroll
    for (int i = 0; i < 2; ++i) {
      const uint4* pp = reinterpret_cast<const uint4*>(
          P + col * 72 + i * 32 + quad * 8);                 // A[m=col][k]
      const uint4* vp = reinterpret_cast<const uint4*>(
          VTb + (((size_t)(b * 16 + col)) << 12) + c * 64 + i * 32 + quad * 8);
      o = __builtin_amdgcn_mfma_f32_16x16x32_bf16(
          as_bf16x8(pp[0]), as_bf16x8(vp[0]), o, 0, 0, 0);
    }
  }

  // reduce per-lane l across the 16-lane group
#pragma unroll
  for (int d = 1; d < 16; d <<= 1) {
#pragma unroll
    for (int r = 0; r < 4; ++r) l_[r] += __shfl_xor(l_[r], d, 16);
  }

  // cross-wave merge via LDS
#pragma unroll
  for (int r = 0; r < 4; ++r) {
    mrg[w][r][lane]     = m_[r];
    mrg[w][4 + r][lane] = l_[r];
    mrg[w][8 + r][lane] = o[r];
  }
  __syncthreads();
  if (w == 0) {
#pragma unroll
    for (int r = 0; r < 4; ++r) {
      float M = mrg[0][r][lane];
#pragma unroll
      for (int w2 = 1; w2 < 4; ++w2) M = fmaxf(M, mrg[w2][r][lane]);
      float L = 0.f, O = 0.f;
#pragma unroll
      for (int w2 = 0; w2 < 4; ++w2) {
        const float sc = exp2f(mrg[w2][r][lane] - M);
        L += mrg[w2][4 + r][lane] * sc;
        O += mrg[w2][8 + r][lane] * sc;
      }
      out[(((size_t)(b * T_SEQ + r0 + quad * 4 + r)) << 4) + col] = O / L;
    }
  }
}

extern "C" void kernel_launch(void* const* d_in, const int* in_sizes, int n_in,
                              void* d_out, int out_size, void* d_ws, size_t ws_size,
                              hipStream_t stream) {
  const float* x  = (const float*)d_in[0];
  const float* Wk = (const float*)d_in[1];
  const float* Wq = (const float*)d_in[2];
  const float* Wv = (const float*)d_in[3];
  float* outp = (float*)d_out;

  // ws (shorts): Qb [NROW*32] | Kb [NROW*16 + 64 slack] | VTb [NROW*16]
  unsigned short* Qb  = (unsigned short*)d_ws;
  unsigned short* Kb  = Qb + (size_t)NROW * 32;
  unsigned short* VTb = Kb + (size_t)NROW * 16 + 64;

  qkv_proj<<<192, 256, 0, stream>>>(x, Wk, Wq, Wv, Kb, Qb, VTb);
  flash_mfma<<<B_DIM * 256, 256, 0, stream>>>(Qb, Kb, VTb, outp);
}

// Round 3
// 116.132 us; speedup vs baseline: 4.9028x; 1.5210x over previous
//
#include <hip/hip_runtime.h>

// Causal attention head. B=4, T=4096, C=384, H=16. fp32 in/out.
// Round 3:
//  - wconv: W fp32 [384][16] x3 -> WT bf16 [3][16][384] (B-frag friendly).
//  - qkv_mfma: x@W via 16x16x32_bf16 MFMA. One wave per 16-row M-tile, all
//    3 matrices. A-frags: preload all 24 float4/lane from global (24 KB in
//    flight per wave -> HBM-bound drain), convert to bf16 per K-iter.
//    B-frags: direct 16B loads from WT (L1-resident, 36 KB).
//  - flash_v3: online-max REMOVED (scores bounded, exp2 can't overflow ->
//    plain sum-of-exp2; masked = exp2(-1e30) = 0; merge = plain sums).
//    Heavy-first block order (qt descending) for LPT packing. V hoisted.
// All MFMA layouts identical to the round-2-verified ones.

constexpr int B_DIM = 4;
constexpr int T_SEQ = 4096;
constexpr int C_DIM = 384;
constexpr int H_DIM = 16;
constexpr int NROW  = B_DIM * T_SEQ; // 16384

typedef __bf16 bf16x8 __attribute__((ext_vector_type(8)));
typedef float  f32x4  __attribute__((ext_vector_type(4)));

__device__ __forceinline__ unsigned short f2bf(float f) {
  unsigned int u = __builtin_bit_cast(unsigned int, f);
  u += 0x7fffu + ((u >> 16) & 1u);   // RNE (finite inputs)
  return (unsigned short)(u >> 16);
}
__device__ __forceinline__ bf16x8 as_bf16x8(uint4 u) {
  return __builtin_bit_cast(bf16x8, u);
}
__device__ __forceinline__ bf16x8 cvt8(float4 a, float4 b) {
  uint4 pk;
  pk.x = (unsigned)f2bf(a.x) | ((unsigned)f2bf(a.y) << 16);
  pk.y = (unsigned)f2bf(a.z) | ((unsigned)f2bf(a.w) << 16);
  pk.z = (unsigned)f2bf(b.x) | ((unsigned)f2bf(b.y) << 16);
  pk.w = (unsigned)f2bf(b.z) | ((unsigned)f2bf(b.w) << 16);
  return as_bf16x8(pk);
}

// ---------------------------------------------------------------------------
// Kernel 0: W -> WT bf16, layout [m][n=16][k=384]. 18432 elements.
// ---------------------------------------------------------------------------
__global__ __launch_bounds__(256) void wconv(
    const float* __restrict__ Wk, const float* __restrict__ Wq,
    const float* __restrict__ Wv, unsigned short* __restrict__ WT) {
  const int i = blockIdx.x * 256 + threadIdx.x;   // grid 72*256 = 18432
  const int m = i / 6144;
  const int r = i - m * 6144;
  const int n = r / 384;
  const int k = r - n * 384;
  const float* __restrict__ W = (m == 0) ? Wk : (m == 1) ? Wq : Wv;
  WT[i] = f2bf(W[k * 16 + n]);
}

// ---------------------------------------------------------------------------
// Kernel 1: QKV projection via MFMA. grid 256 blocks x 4 waves = 1024 waves,
// wave -> M-tile of 16 rows, K-loop 12 x 32.
// A-frag: A[m=col][k=quad*8+j] ; B-frag: B[k=quad*8+j][n=col] from WT.
// C-frag: row = quad*4+r, col = lane&15 (r2-verified).
// ---------------------------------------------------------------------------
__global__ __launch_bounds__(256) void qkv_mfma(
    const float* __restrict__ x, const unsigned short* __restrict__ WT,
    unsigned short* __restrict__ Kb,   // [NROW][16]
    unsigned short* __restrict__ Qb,   // [NROW][32] scaled + zero-padded
    unsigned short* __restrict__ VTb)  // [B][16][T]
{
  const int tid  = threadIdx.x;
  const int w    = tid >> 6;
  const int lane = tid & 63;
  const int quad = lane >> 4;
  const int col  = lane & 15;
  const int mt   = blockIdx.x * 4 + w;   // 0..1023
  const int r0   = mt << 4;

  // preload the wave's entire A panel: 16 rows x 384 floats -> 24 float4/lane
  const float4* __restrict__ xp =
      reinterpret_cast<const float4*>(x + (size_t)(r0 + col) * C_DIM) + quad * 2;
  float4 araw[24];
#pragma unroll
  for (int kk = 0; kk < 12; ++kk) {
    araw[2 * kk]     = xp[kk * 8];
    araw[2 * kk + 1] = xp[kk * 8 + 1];
  }

  const uint4* __restrict__ bk = reinterpret_cast<const uint4*>(
      WT + (size_t)col * 384 + quad * 8);
  const uint4* __restrict__ bq = reinterpret_cast<const uint4*>(
      WT + 6144 + (size_t)col * 384 + quad * 8);
  const uint4* __restrict__ bv = reinterpret_cast<const uint4*>(
      WT + 12288 + (size_t)col * 384 + quad * 8);

  f32x4 ck = {0.f, 0.f, 0.f, 0.f};
  f32x4 cq = {0.f, 0.f, 0.f, 0.f};
  f32x4 cv = {0.f, 0.f, 0.f, 0.f};
#pragma unroll
  for (int kk = 0; kk < 12; ++kk) {
    const bf16x8 av = cvt8(araw[2 * kk], araw[2 * kk + 1]);
    ck = __builtin_amdgcn_mfma_f32_16x16x32_bf16(av, as_bf16x8(bk[kk * 4]), ck, 0, 0, 0);
    cq = __builtin_amdgcn_mfma_f32_16x16x32_bf16(av, as_bf16x8(bq[kk * 4]), cq, 0, 0, 0);
    cv = __builtin_amdgcn_mfma_f32_16x16x32_bf16(av, as_bf16x8(bv[kk * 4]), cv, 0, 0, 0);
  }

  const float SC = 0.25f * 1.44269504088896341f;  // softmax scale * log2(e)
#pragma unroll
  for (int r = 0; r < 4; ++r) {
    const int row = r0 + quad * 4 + r;
    Kb[row * 16 + col]      = f2bf(ck[r]);
    Qb[row * 32 + col]      = f2bf(cq[r] * SC);
    Qb[row * 32 + 16 + col] = 0;
    const int bb = row >> 12, t = row & 4095;
    VTb[(((size_t)(bb * 16 + col)) << 12) + t] = f2bf(cv[r]);
  }
}

// ---------------------------------------------------------------------------
// Kernel 2: bf16 MFMA flash attention, no online max.
// blk -> qtp = blk>>2 (heavy first: qt = 255-qtp), b = blk&3.
// 4 waves split 64-key chunks; merge = plain sums of (l, o) via LDS.
// ---------------------------------------------------------------------------
__global__ __launch_bounds__(256) void flash_v3(
    const unsigned short* __restrict__ Qb,
    const unsigned short* __restrict__ Kb,
    const unsigned short* __restrict__ VTb,
    float* __restrict__ out)
{
  const int tid  = threadIdx.x;
  const int w    = tid >> 6;
  const int lane = tid & 63;
  const int quad = lane >> 4;
  const int col  = lane & 15;
  const int b    = blockIdx.x & 3;
  const int qt   = 255 - (blockIdx.x >> 2);   // heavy blocks dispatch first
  const int r0   = qt << 4;

  __shared__ __attribute__((aligned(16))) unsigned short Pl[4][16 * 72];
  __shared__ float mrg[4][8][64];

  const uint4* qp = reinterpret_cast<const uint4*>(
      Qb + (((size_t)(b * T_SEQ + r0 + col)) << 5) + quad * 8);
  const bf16x8 qa = as_bf16x8(qp[0]);

  f32x4 o = {0.f, 0.f, 0.f, 0.f};
  float l_[4] = {0.f, 0.f, 0.f, 0.f};

  unsigned short* P = Pl[w];
  const unsigned short* Kbase = Kb + ((size_t)(b * T_SEQ) << 4);
  const unsigned short* Vbase = VTb + (((size_t)(b * 16 + col)) << 12);
  const int nch = (qt + 4) >> 2;

  for (int c = w; c < nch; c += 4) {
    const int kt0 = c << 2;
    f32x4 sf[4];
#pragma unroll
    for (int t = 0; t < 4; ++t) {
      const int kt = kt0 + t;
      if (kt <= qt) {
        const uint4* kp = reinterpret_cast<const uint4*>(
            Kbase + (((size_t)(kt * 16 + col)) << 4) + quad * 8);
        f32x4 z = {0.f, 0.f, 0.f, 0.f};
        sf[t] = __builtin_amdgcn_mfma_f32_16x16x32_bf16(qa, as_bf16x8(kp[0]), z, 0, 0, 0);
      } else {
#pragma unroll
        for (int r = 0; r < 4; ++r) sf[t][r] = -1e30f;
      }
    }
    // causal mask on the diagonal tile (kt == qt)
    {
      const int td = qt - kt0;
      if (td >= 0 && td < 4) {
#pragma unroll
        for (int r = 0; r < 4; ++r)
          if (col > quad * 4 + r) sf[td][r] = -1e30f;
      }
    }

    // V fragments hoisted (independent of softmax chain)
    const uint4 v0 = *reinterpret_cast<const uint4*>(Vbase + c * 64 + quad * 8);
    const uint4 v1 = *reinterpret_cast<const uint4*>(Vbase + c * 64 + 32 + quad * 8);

    // p = exp2(s); masked lanes give exp2(-1e30) = 0. No max tracking:
    // |s*scale*log2e| is bounded far below 127, fp32 exp2 cannot overflow.
#pragma unroll
    for (int t = 0; t < 4; ++t) {
#pragma unroll
      for (int r = 0; r < 4; ++r) {
        const float p = exp2f(sf[t][r]);
        l_[r] += p;
        P[(quad * 4 + r) * 72 + t * 16 + col] = f2bf(p);
      }
    }

    const uint4 p0 = *reinterpret_cast<const uint4*>(P + col * 72 + quad * 8);
    const uint4 p1 = *reinterpret_cast<const uint4*>(P + col * 72 + 32 + quad * 8);
    o = __builtin_amdgcn_mfma_f32_16x16x32_bf16(as_bf16x8(p0), as_bf16x8(v0), o, 0, 0, 0);
    o = __builtin_amdgcn_mfma_f32_16x16x32_bf16(as_bf16x8(p1), as_bf16x8(v1), o, 0, 0, 0);
  }

  // l: partial row-sums live across the 16-lane group -> reduce
#pragma unroll
  for (int d = 1; d < 16; d <<= 1) {
#pragma unroll
    for (int r = 0; r < 4; ++r) l_[r] += __shfl_xor(l_[r], d, 16);
  }

  // cross-wave merge: plain sums (no max scaling needed)
#pragma unroll
  for (int r = 0; r < 4; ++r) {
    mrg[w][r][lane]     = l_[r];
    mrg[w][4 + r][lane] = o[r];
  }
  __syncthreads();
  if (w == 0) {
#pragma unroll
    for (int r = 0; r < 4; ++r) {
      const float L = mrg[0][r][lane] + mrg[1][r][lane] +
                      mrg[2][r][lane] + mrg[3][r][lane];
      const float O = mrg[0][4 + r][lane] + mrg[1][4 + r][lane] +
                      mrg[2][4 + r][lane] + mrg[3][4 + r][lane];
      out[(((size_t)(b * T_SEQ + r0 + quad * 4 + r)) << 4) + col] = O / L;
    }
  }
}

extern "C" void kernel_launch(void* const* d_in, const int* in_sizes, int n_in,
                              void* d_out, int out_size, void* d_ws, size_t ws_size,
                              hipStream_t stream) {
  const float* x  = (const float*)d_in[0];
  const float* Wk = (const float*)d_in[1];
  const float* Wq = (const float*)d_in[2];
  const float* Wv = (const float*)d_in[3];
  float* outp = (float*)d_out;

  // ws (shorts): Qb [NROW*32] | Kb [NROW*16] | 64 slack | VTb [NROW*16] | WT [18432]
  unsigned short* Qb  = (unsigned short*)d_ws;
  unsigned short* Kb  = Qb + (size_t)NROW * 32;
  unsigned short* VTb = Kb + (size_t)NROW * 16 + 64;
  unsigned short* WT  = VTb + (size_t)NROW * 16;

  wconv<<<72, 256, 0, stream>>>(Wk, Wq, Wv, WT);
  qkv_mfma<<<256, 256, 0, stream>>>(x, WT, Kb, Qb, VTb);
  flash_v3<<<B_DIM * 256, 256, 0, stream>>>(Qb, Kb, VTb, outp);
}

// Round 5
// 109.159 us; speedup vs baseline: 5.2160x; 1.0639x over previous
//
#include <hip/hip_runtime.h>

// Causal attention head. B=4, T=4096, C=384, H=16. fp32 in/out.
// Round 5 = Round 4 with the qkv weight-pointer units bug fixed:
//   bq/bv are uint4* (8 shorts/elem); "+6144 shorts" = +768 uint4, not +192.
//   (R4 pointed bq/bv inside the Wk region -> garbage Q and V.)
// Also dropped __restrict__ on the flash lambda P params (aliasing-UB risk).
//  - Known: harness re-poison of 256MB d_ws + d_in restore ~= 52us fixed floor.
//  - flash_v4: software-pipelined PV (one chunk behind), double-buffered
//    static P tiles, native v_exp_f32, no online max (scores bounded).
//  - qkv_mfma: 2-way K-split (128-thr blocks, 1024 blocks), LDS merge.

constexpr int B_DIM = 4;
constexpr int T_SEQ = 4096;
constexpr int C_DIM = 384;
constexpr int H_DIM = 16;
constexpr int NROW  = B_DIM * T_SEQ; // 16384

typedef __bf16 bf16x8 __attribute__((ext_vector_type(8)));
typedef float  f32x4  __attribute__((ext_vector_type(4)));

__device__ __forceinline__ unsigned short f2bf(float f) {
  unsigned int u = __builtin_bit_cast(unsigned int, f);
  u += 0x7fffu + ((u >> 16) & 1u);   // RNE (finite inputs)
  return (unsigned short)(u >> 16);
}
__device__ __forceinline__ bf16x8 as_bf16x8(uint4 u) {
  return __builtin_bit_cast(bf16x8, u);
}

// ---------------------------------------------------------------------------
// Kernel 0: W -> WT bf16, layout [m][n=16][k=384]. 18432 elements.
// ---------------------------------------------------------------------------
__global__ __launch_bounds__(256) void wconv(
    const float* __restrict__ Wk, const float* __restrict__ Wq,
    const float* __restrict__ Wv, unsigned short* __restrict__ WT) {
  const int i = blockIdx.x * 256 + threadIdx.x;   // grid 72*256 = 18432
  const int m = i / 6144;
  const int r = i - m * 6144;
  const int n = r / 384;
  const int k = r - n * 384;
  const float* __restrict__ W = (m == 0) ? Wk : (m == 1) ? Wq : Wv;
  WT[i] = f2bf(W[k * 16 + n]);
}

// ---------------------------------------------------------------------------
// Kernel 1: QKV projection via MFMA, 2-way K-split.
// block = 128 thr (2 waves), grid = 1024 blocks (one 16-row M-tile each).
// wave w does kk = w*6 .. w*6+5 (6 x K=32); LDS merge; wave 0 epilogue.
// A-frag: A[m=col][k=quad*8+j]; B-frag from WT; C: row=quad*4+r, col.
// ---------------------------------------------------------------------------
__global__ __launch_bounds__(128) void qkv_mfma(
    const float* __restrict__ x, const unsigned short* __restrict__ WT,
    unsigned short* __restrict__ Kb,   // [NROW][16]
    unsigned short* __restrict__ Qb,   // [NROW][32] scaled + zero-padded
    unsigned short* __restrict__ VTb)  // [B][16][T]
{
  const int tid  = threadIdx.x;
  const int w    = tid >> 6;           // 0..1
  const int lane = tid & 63;
  const int quad = lane >> 4;
  const int col  = lane & 15;
  const int r0   = blockIdx.x << 4;
  const int kb   = w * 6;              // this wave's kk base

  __shared__ float mrg[12][64];

  // preload this wave's half A panel: 6 K-iters -> 12 float4/lane
  const float4* __restrict__ xp =
      reinterpret_cast<const float4*>(x + (size_t)(r0 + col) * C_DIM) + quad * 2;
  float4 araw[12];
#pragma unroll
  for (int kk = 0; kk < 6; ++kk) {
    araw[2 * kk]     = xp[(kb + kk) * 8];
    araw[2 * kk + 1] = xp[(kb + kk) * 8 + 1];
  }

  const uint4* __restrict__ bk = reinterpret_cast<const uint4*>(
      WT + (size_t)col * 384 + quad * 8);
  const uint4* __restrict__ bq = bk + 768;    // +6144 shorts = 768 uint4 (FIX)
  const uint4* __restrict__ bv = bk + 1536;   // +12288 shorts = 1536 uint4 (FIX)

  f32x4 ck = {0.f, 0.f, 0.f, 0.f};
  f32x4 cq = {0.f, 0.f, 0.f, 0.f};
  f32x4 cv = {0.f, 0.f, 0.f, 0.f};
#pragma unroll
  for (int kk = 0; kk < 6; ++kk) {
    uint4 pk;
    const float4 a0 = araw[2 * kk], a1 = araw[2 * kk + 1];
    pk.x = (unsigned)f2bf(a0.x) | ((unsigned)f2bf(a0.y) << 16);
    pk.y = (unsigned)f2bf(a0.z) | ((unsigned)f2bf(a0.w) << 16);
    pk.z = (unsigned)f2bf(a1.x) | ((unsigned)f2bf(a1.y) << 16);
    pk.w = (unsigned)f2bf(a1.z) | ((unsigned)f2bf(a1.w) << 16);
    const bf16x8 av = as_bf16x8(pk);
    ck = __builtin_amdgcn_mfma_f32_16x16x32_bf16(av, as_bf16x8(bk[(kb + kk) * 4]), ck, 0, 0, 0);
    cq = __builtin_amdgcn_mfma_f32_16x16x32_bf16(av, as_bf16x8(bq[(kb + kk) * 4]), cq, 0, 0, 0);
    cv = __builtin_amdgcn_mfma_f32_16x16x32_bf16(av, as_bf16x8(bv[(kb + kk) * 4]), cv, 0, 0, 0);
  }

  if (w == 1) {
#pragma unroll
    for (int r = 0; r < 4; ++r) {
      mrg[r][lane]     = ck[r];
      mrg[4 + r][lane] = cq[r];
      mrg[8 + r][lane] = cv[r];
    }
  }
  __syncthreads();
  if (w == 0) {
    const float SC = 0.25f * 1.44269504088896341f;  // softmax scale * log2(e)
#pragma unroll
    for (int r = 0; r < 4; ++r) {
      const float vk = ck[r] + mrg[r][lane];
      const float vq = cq[r] + mrg[4 + r][lane];
      const float vv = cv[r] + mrg[8 + r][lane];
      const int row = r0 + quad * 4 + r;
      Kb[row * 16 + col]      = f2bf(vk);
      Qb[row * 32 + col]      = f2bf(vq * SC);
      Qb[row * 32 + 16 + col] = 0;
      const int bb = row >> 12, t = row & 4095;
      VTb[(((size_t)(bb * 16 + col)) << 12) + t] = f2bf(vv);
    }
  }
}

// ---------------------------------------------------------------------------
// Kernel 2: bf16 MFMA flash attention, no online max, software-pipelined PV.
// blk -> qt = 255-(blk>>2) (heavy first), b = blk&3. 4 waves split 64-key
// chunks. P double-buffered (static P0/P1) so PV of chunk i overlaps the
// exp/QK of chunk i+1 and never waits on just-issued LDS writes.
// ---------------------------------------------------------------------------
__global__ __launch_bounds__(256) void flash_v4(
    const unsigned short* __restrict__ Qb,
    const unsigned short* __restrict__ Kb,
    const unsigned short* __restrict__ VTb,
    float* __restrict__ out)
{
  const int tid  = threadIdx.x;
  const int w    = tid >> 6;
  const int lane = tid & 63;
  const int quad = lane >> 4;
  const int col  = lane & 15;
  const int b    = blockIdx.x & 3;
  const int qt   = 255 - (blockIdx.x >> 2);
  const int r0   = qt << 4;

  __shared__ __attribute__((aligned(16))) unsigned short Pl[4][2][16 * 72];
  __shared__ float mrg[4][8][64];

  const uint4* qp = reinterpret_cast<const uint4*>(
      Qb + (((size_t)(b * T_SEQ + r0 + col)) << 5) + quad * 8);
  const bf16x8 qa = as_bf16x8(qp[0]);

  f32x4 o = {0.f, 0.f, 0.f, 0.f};
  float l_[4] = {0.f, 0.f, 0.f, 0.f};

  const unsigned short* Kbase = Kb + ((size_t)(b * T_SEQ) << 4);
  const unsigned short* Vbase = VTb + (((size_t)(b * 16 + col)) << 12);
  const int nch = (qt + 4) >> 2;

  unsigned short* const P0 = Pl[w][0];
  unsigned short* const P1 = Pl[w][1];

  // QK -> mask -> exp -> write P tile for chunk c
  auto computeP = [&](int c, unsigned short* P) {
    const int kt0 = c << 2;
    f32x4 sf[4];
#pragma unroll
    for (int t = 0; t < 4; ++t) {
      const int kt = kt0 + t;
      if (kt <= qt) {
        const uint4* kp = reinterpret_cast<const uint4*>(
            Kbase + (((size_t)(kt * 16 + col)) << 4) + quad * 8);
        f32x4 z = {0.f, 0.f, 0.f, 0.f};
        sf[t] = __builtin_amdgcn_mfma_f32_16x16x32_bf16(qa, as_bf16x8(kp[0]), z, 0, 0, 0);
      } else {
#pragma unroll
        for (int r = 0; r < 4; ++r) sf[t][r] = -1e30f;
      }
    }
    const int td = qt - kt0;
    if (td >= 0 && td < 4) {
#pragma unroll
      for (int r = 0; r < 4; ++r)
        if (col > quad * 4 + r) sf[td][r] = -1e30f;
    }
#pragma unroll
    for (int t = 0; t < 4; ++t) {
#pragma unroll
      for (int r = 0; r < 4; ++r) {
        const float p = __builtin_amdgcn_exp2f(sf[t][r]);  // v_exp_f32; -1e30 -> 0
        l_[r] += p;
        P[(quad * 4 + r) * 72 + t * 16 + col] = f2bf(p);
      }
    }
  };

  // O += P(chunk c) @ V(chunk c)
  auto doPV = [&](int c, const unsigned short* P) {
    const uint4 v0 = *reinterpret_cast<const uint4*>(Vbase + c * 64 + quad * 8);
    const uint4 v1 = *reinterpret_cast<const uint4*>(Vbase + c * 64 + 32 + quad * 8);
    const uint4 p0 = *reinterpret_cast<const uint4*>(P + col * 72 + quad * 8);
    const uint4 p1 = *reinterpret_cast<const uint4*>(P + col * 72 + 32 + quad * 8);
    o = __builtin_amdgcn_mfma_f32_16x16x32_bf16(as_bf16x8(p0), as_bf16x8(v0), o, 0, 0, 0);
    o = __builtin_amdgcn_mfma_f32_16x16x32_bf16(as_bf16x8(p1), as_bf16x8(v1), o, 0, 0, 0);
  };

  int c = w;
  if (c < nch) {
    computeP(c, P0);
    int last = c; c += 4;
    while (c < nch) {
      computeP(c, P1);     // fill P1 while...
      doPV(last, P0);      // ...consuming P0 (written last stage, drained)
      last = c; c += 4;
      if (c >= nch) { doPV(last, P1); last = -1; break; }
      computeP(c, P0);
      doPV(last, P1);
      last = c; c += 4;
    }
    if (last >= 0) doPV(last, P0);
  }

  // l: partial row-sums across the 16-lane group -> reduce
#pragma unroll
  for (int d = 1; d < 16; d <<= 1) {
#pragma unroll
    for (int r = 0; r < 4; ++r) l_[r] += __shfl_xor(l_[r], d, 16);
  }

  // cross-wave merge: plain sums
#pragma unroll
  for (int r = 0; r < 4; ++r) {
    mrg[w][r][lane]     = l_[r];
    mrg[w][4 + r][lane] = o[r];
  }
  __syncthreads();
  if (w == 0) {
#pragma unroll
    for (int r = 0; r < 4; ++r) {
      const float L = mrg[0][r][lane] + mrg[1][r][lane] +
                      mrg[2][r][lane] + mrg[3][r][lane];
      const float O = mrg[0][4 + r][lane] + mrg[1][4 + r][lane] +
                      mrg[2][4 + r][lane] + mrg[3][4 + r][lane];
      out[(((size_t)(b * T_SEQ + r0 + quad * 4 + r)) << 4) + col] = O / L;
    }
  }
}

extern "C" void kernel_launch(void* const* d_in, const int* in_sizes, int n_in,
                              void* d_out, int out_size, void* d_ws, size_t ws_size,
                              hipStream_t stream) {
  const float* x  = (const float*)d_in[0];
  const float* Wk = (const float*)d_in[1];
  const float* Wq = (const float*)d_in[2];
  const float* Wv = (const float*)d_in[3];
  float* outp = (float*)d_out;

  // ws (shorts): Qb [NROW*32] | Kb [NROW*16] | 64 slack | VTb [NROW*16] | WT [18432]
  unsigned short* Qb  = (unsigned short*)d_ws;
  unsigned short* Kb  = Qb + (size_t)NROW * 32;
  unsigned short* VTb = Kb + (size_t)NROW * 16 + 64;
  unsigned short* WT  = VTb + (size_t)NROW * 16;

  wconv<<<72, 256, 0, stream>>>(Wk, Wq, Wv, WT);
  qkv_mfma<<<1024, 128, 0, stream>>>(x, WT, Kb, Qb, VTb);
  flash_v4<<<B_DIM * 256, 256, 0, stream>>>(Qb, Kb, VTb, outp);
}

// Round 6
// 103.992 us; speedup vs baseline: 5.4751x; 1.0497x over previous
//
#include <hip/hip_runtime.h>

// Causal attention head. B=4, T=4096, C=384, H=16. fp32 in/out.
// Round 6: flash occupancy attack (R4/R5 intra-wave pipelining was ~neutral ->
// per-wave serial chains at 4 waves/SIMD are the bottleneck; go TLP):
//  - flash_v5: key-range split x2 across blocks -> grid 2048, 8 key-slots
//    per (b,qt). No online max -> partials are plain sums -> each wave writes
//    (O,l) partials to ws directly: NO LDS merge, NO syncthreads. LDS = P
//    tiles only (18.4 KB) -> 8 blocks/CU = 32 waves/CU (occupancy max).
//  - flash_merge: out = sum(O_partials) / sum(l_partials). 1 MB out, ~2us.
//  - qkv_mfma / wconv unchanged from R5.
// Fixed harness floor ~52us (256MB ws re-poison 44us + restores) on top.

constexpr int B_DIM = 4;
constexpr int T_SEQ = 4096;
constexpr int C_DIM = 384;
constexpr int H_DIM = 16;
constexpr int NROW  = B_DIM * T_SEQ; // 16384

typedef __bf16 bf16x8 __attribute__((ext_vector_type(8)));
typedef float  f32x4  __attribute__((ext_vector_type(4)));

__device__ __forceinline__ unsigned short f2bf(float f) {
  unsigned int u = __builtin_bit_cast(unsigned int, f);
  u += 0x7fffu + ((u >> 16) & 1u);   // RNE (finite inputs)
  return (unsigned short)(u >> 16);
}
__device__ __forceinline__ bf16x8 as_bf16x8(uint4 u) {
  return __builtin_bit_cast(bf16x8, u);
}

// ---------------------------------------------------------------------------
// Kernel 0: W -> WT bf16, layout [m][n=16][k=384]. 18432 elements.
// ---------------------------------------------------------------------------
__global__ __launch_bounds__(256) void wconv(
    const float* __restrict__ Wk, const float* __restrict__ Wq,
    const float* __restrict__ Wv, unsigned short* __restrict__ WT) {
  const int i = blockIdx.x * 256 + threadIdx.x;   // grid 72*256 = 18432
  const int m = i / 6144;
  const int r = i - m * 6144;
  const int n = r / 384;
  const int k = r - n * 384;
  const float* __restrict__ W = (m == 0) ? Wk : (m == 1) ? Wq : Wv;
  WT[i] = f2bf(W[k * 16 + n]);
}

// ---------------------------------------------------------------------------
// Kernel 1: QKV projection via MFMA, 2-way K-split (unchanged from R5).
// ---------------------------------------------------------------------------
__global__ __launch_bounds__(128) void qkv_mfma(
    const float* __restrict__ x, const unsigned short* __restrict__ WT,
    unsigned short* __restrict__ Kb,   // [NROW][16]
    unsigned short* __restrict__ Qb,   // [NROW][32] scaled + zero-padded
    unsigned short* __restrict__ VTb)  // [B][16][T]
{
  const int tid  = threadIdx.x;
  const int w    = tid >> 6;           // 0..1
  const int lane = tid & 63;
  const int quad = lane >> 4;
  const int col  = lane & 15;
  const int r0   = blockIdx.x << 4;
  const int kb   = w * 6;              // this wave's kk base

  __shared__ float mrg[12][64];

  const float4* __restrict__ xp =
      reinterpret_cast<const float4*>(x + (size_t)(r0 + col) * C_DIM) + quad * 2;
  float4 araw[12];
#pragma unroll
  for (int kk = 0; kk < 6; ++kk) {
    araw[2 * kk]     = xp[(kb + kk) * 8];
    araw[2 * kk + 1] = xp[(kb + kk) * 8 + 1];
  }

  const uint4* __restrict__ bk = reinterpret_cast<const uint4*>(
      WT + (size_t)col * 384 + quad * 8);
  const uint4* __restrict__ bq = bk + 768;    // +6144 shorts
  const uint4* __restrict__ bv = bk + 1536;   // +12288 shorts

  f32x4 ck = {0.f, 0.f, 0.f, 0.f};
  f32x4 cq = {0.f, 0.f, 0.f, 0.f};
  f32x4 cv = {0.f, 0.f, 0.f, 0.f};
#pragma unroll
  for (int kk = 0; kk < 6; ++kk) {
    uint4 pk;
    const float4 a0 = araw[2 * kk], a1 = araw[2 * kk + 1];
    pk.x = (unsigned)f2bf(a0.x) | ((unsigned)f2bf(a0.y) << 16);
    pk.y = (unsigned)f2bf(a0.z) | ((unsigned)f2bf(a0.w) << 16);
    pk.z = (unsigned)f2bf(a1.x) | ((unsigned)f2bf(a1.y) << 16);
    pk.w = (unsigned)f2bf(a1.z) | ((unsigned)f2bf(a1.w) << 16);
    const bf16x8 av = as_bf16x8(pk);
    ck = __builtin_amdgcn_mfma_f32_16x16x32_bf16(av, as_bf16x8(bk[(kb + kk) * 4]), ck, 0, 0, 0);
    cq = __builtin_amdgcn_mfma_f32_16x16x32_bf16(av, as_bf16x8(bq[(kb + kk) * 4]), cq, 0, 0, 0);
    cv = __builtin_amdgcn_mfma_f32_16x16x32_bf16(av, as_bf16x8(bv[(kb + kk) * 4]), cv, 0, 0, 0);
  }

  if (w == 1) {
#pragma unroll
    for (int r = 0; r < 4; ++r) {
      mrg[r][lane]     = ck[r];
      mrg[4 + r][lane] = cq[r];
      mrg[8 + r][lane] = cv[r];
    }
  }
  __syncthreads();
  if (w == 0) {
    const float SC = 0.25f * 1.44269504088896341f;  // softmax scale * log2(e)
#pragma unroll
    for (int r = 0; r < 4; ++r) {
      const float vk = ck[r] + mrg[r][lane];
      const float vq = cq[r] + mrg[4 + r][lane];
      const float vv = cv[r] + mrg[8 + r][lane];
      const int row = r0 + quad * 4 + r;
      Kb[row * 16 + col]      = f2bf(vk);
      Qb[row * 32 + col]      = f2bf(vq * SC);
      Qb[row * 32 + 16 + col] = 0;
      const int bb = row >> 12, t = row & 4095;
      VTb[(((size_t)(bb * 16 + col)) << 12) + t] = f2bf(vv);
    }
  }
}

// ---------------------------------------------------------------------------
// Kernel 2: bf16 MFMA flash attention, key-split x2, per-wave global partials.
// grid 2048: blk = qtp*8 + b*2 + h (heavy qt first). slot = h*4 + w in [0,8).
// Wave handles chunks c = slot, slot+8, ... < nch. Writes (O,l) partial sums
// to PO[slot][row][16] / PL[slot][row]; idle waves write zeros.
// P tiles double-buffered (kept from R5; harmless). No barriers at all.
// ---------------------------------------------------------------------------
__global__ __launch_bounds__(256) void flash_v5(
    const unsigned short* __restrict__ Qb,
    const unsigned short* __restrict__ Kb,
    const unsigned short* __restrict__ VTb,
    float* __restrict__ PO, float* __restrict__ PL)
{
  const int tid  = threadIdx.x;
  const int w    = tid >> 6;
  const int lane = tid & 63;
  const int quad = lane >> 4;
  const int col  = lane & 15;
  const int qt   = 255 - (blockIdx.x >> 3);   // heavy first
  const int b    = (blockIdx.x >> 1) & 3;
  const int h    = blockIdx.x & 1;
  const int slot = h * 4 + w;                 // 0..7
  const int r0   = qt << 4;

  __shared__ __attribute__((aligned(16))) unsigned short Pl[4][2][16 * 72];

  const uint4* qp = reinterpret_cast<const uint4*>(
      Qb + (((size_t)(b * T_SEQ + r0 + col)) << 5) + quad * 8);
  const bf16x8 qa = as_bf16x8(qp[0]);

  f32x4 o = {0.f, 0.f, 0.f, 0.f};
  float l_[4] = {0.f, 0.f, 0.f, 0.f};

  const unsigned short* Kbase = Kb + ((size_t)(b * T_SEQ) << 4);
  const unsigned short* Vbase = VTb + (((size_t)(b * 16 + col)) << 12);
  const int nch = (qt + 4) >> 2;

  unsigned short* const P0 = Pl[w][0];
  unsigned short* const P1 = Pl[w][1];

  auto computeP = [&](int c, unsigned short* P) {
    const int kt0 = c << 2;
    f32x4 sf[4];
#pragma unroll
    for (int t = 0; t < 4; ++t) {
      const int kt = kt0 + t;
      if (kt <= qt) {
        const uint4* kp = reinterpret_cast<const uint4*>(
            Kbase + (((size_t)(kt * 16 + col)) << 4) + quad * 8);
        f32x4 z = {0.f, 0.f, 0.f, 0.f};
        sf[t] = __builtin_amdgcn_mfma_f32_16x16x32_bf16(qa, as_bf16x8(kp[0]), z, 0, 0, 0);
      } else {
#pragma unroll
        for (int r = 0; r < 4; ++r) sf[t][r] = -1e30f;
      }
    }
    const int td = qt - kt0;
    if (td >= 0 && td < 4) {
#pragma unroll
      for (int r = 0; r < 4; ++r)
        if (col > quad * 4 + r) sf[td][r] = -1e30f;
    }
#pragma unroll
    for (int t = 0; t < 4; ++t) {
#pragma unroll
      for (int r = 0; r < 4; ++r) {
        const float p = __builtin_amdgcn_exp2f(sf[t][r]);  // -1e30 -> 0
        l_[r] += p;
        P[(quad * 4 + r) * 72 + t * 16 + col] = f2bf(p);
      }
    }
  };

  auto doPV = [&](int c, const unsigned short* P) {
    const uint4 v0 = *reinterpret_cast<const uint4*>(Vbase + c * 64 + quad * 8);
    const uint4 v1 = *reinterpret_cast<const uint4*>(Vbase + c * 64 + 32 + quad * 8);
    const uint4 p0 = *reinterpret_cast<const uint4*>(P + col * 72 + quad * 8);
    const uint4 p1 = *reinterpret_cast<const uint4*>(P + col * 72 + 32 + quad * 8);
    o = __builtin_amdgcn_mfma_f32_16x16x32_bf16(as_bf16x8(p0), as_bf16x8(v0), o, 0, 0, 0);
    o = __builtin_amdgcn_mfma_f32_16x16x32_bf16(as_bf16x8(p1), as_bf16x8(v1), o, 0, 0, 0);
  };

  int c = slot;
  if (c < nch) {
    computeP(c, P0);
    int last = c; c += 8;
    while (c < nch) {
      computeP(c, P1);
      doPV(last, P0);
      last = c; c += 8;
      if (c >= nch) { doPV(last, P1); last = -1; break; }
      computeP(c, P0);
      doPV(last, P1);
      last = c; c += 8;
    }
    if (last >= 0) doPV(last, P0);
  }

  // reduce l across the 16-lane (col) group sharing each row
#pragma unroll
  for (int d = 1; d < 16; d <<= 1) {
#pragma unroll
    for (int r = 0; r < 4; ++r) l_[r] += __shfl_xor(l_[r], d, 16);
  }

  // write partials (zeros if this wave had no chunks)
  const size_t rowbase = (size_t)b * T_SEQ + r0;
  float* pO = PO + ((size_t)slot * NROW + rowbase) * 16;
#pragma unroll
  for (int r = 0; r < 4; ++r) {
    pO[(quad * 4 + r) * 16 + col] = o[r];
    if (col == 0) PL[(size_t)slot * NROW + rowbase + quad * 4 + r] = l_[r];
  }
}

// ---------------------------------------------------------------------------
// Kernel 3: merge 8 partial slots: out = sum(O) / sum(l).
// ---------------------------------------------------------------------------
__global__ __launch_bounds__(256) void flash_merge(
    const float* __restrict__ PO, const float* __restrict__ PL,
    float* __restrict__ out)
{
  const int i   = blockIdx.x * 256 + threadIdx.x;   // grid 1024*256 = 262144
  const int row = i >> 4;
  float O = 0.f, L = 0.f;
#pragma unroll
  for (int s = 0; s < 8; ++s) {
    O += PO[((size_t)s * NROW) * 16 + i];
    L += PL[(size_t)s * NROW + row];
  }
  out[i] = O / L;
}

extern "C" void kernel_launch(void* const* d_in, const int* in_sizes, int n_in,
                              void* d_out, int out_size, void* d_ws, size_t ws_size,
                              hipStream_t stream) {
  const float* x  = (const float*)d_in[0];
  const float* Wk = (const float*)d_in[1];
  const float* Wq = (const float*)d_in[2];
  const float* Wv = (const float*)d_in[3];
  float* outp = (float*)d_out;

  // ws: Qb [NROW*32]sh | Kb [NROW*16]sh | 64 slack | VTb [NROW*16]sh |
  //     WT [18432]sh | PO [8*NROW*16]f32 | PL [8*NROW]f32   (~11 MB total)
  unsigned short* Qb  = (unsigned short*)d_ws;
  unsigned short* Kb  = Qb + (size_t)NROW * 32;
  unsigned short* VTb = Kb + (size_t)NROW * 16 + 64;
  unsigned short* WT  = VTb + (size_t)NROW * 16;
  float* PO = (float*)(WT + 18432);
  float* PL = PO + (size_t)8 * NROW * 16;

  wconv<<<72, 256, 0, stream>>>(Wk, Wq, Wv, WT);
  qkv_mfma<<<1024, 128, 0, stream>>>(x, WT, Kb, Qb, VTb);
  flash_v5<<<2048, 256, 0, stream>>>(Qb, Kb, VTb, PO, PL);
  flash_merge<<<1024, 256, 0, stream>>>(PO, PL, outp);
}